// Round 7
// baseline (10541.371 us; speedup 1.0000x reference)
//
#include <hip/hip_runtime.h>
#include <hip/hip_bf16.h>
#include <cstdint>

#define BATCH 4096
#define DIM   512
#define HID   1024
#define TSTEPS 20
#define NBLK  128
#define NTHR  512

typedef unsigned short u16;
typedef short s16x8 __attribute__((ext_vector_type(8)));
typedef float f32x4 __attribute__((ext_vector_type(4)));

__device__ __forceinline__ u16 f2bf(float f) {
    unsigned int u = __float_as_uint(f);
    u = (u + 0x7FFFu + ((u >> 16) & 1u)) >> 16;   // RNE
    return (u16)u;
}

__device__ __forceinline__ float fast_tanh(float x) {
    float ax = __builtin_fabsf(x);
    float e  = __expf(2.0f * ax);                 // inf for large ax -> t = 1
    float t  = 1.0f - 2.0f * __builtin_amdgcn_rcpf(e + 1.0f);
    return __builtin_copysignf(t, x);
}

// Pack W1 [512k][1024n] f32 -> W1P bf16 in MFMA B-frag order:
// u16 idx = (((w*16 + ks)*8 + cg)*64 + lane)*8 + e
__global__ void pack_w1(const float* __restrict__ W1, u16* __restrict__ W1P) {
    int pid = blockIdx.x * 256 + threadIdx.x;
    int e  = pid & 7;
    int l  = (pid >> 3) & 63;
    int cg = (pid >> 9) & 7;
    int ks = (pid >> 12) & 15;
    int w  = (pid >> 16) & 7;
    int n = w * 128 + cg * 16 + (l & 15);
    int k = ks * 32 + (l >> 4) * 8 + e;
    W1P[pid] = f2bf(W1[(size_t)k * HID + n]);
}

// Pack W2 [1024k][512n] f32 -> W2P bf16:
// u16 idx = (((w*32 + ks)*4 + cf)*64 + lane)*8 + e
__global__ void pack_w2(const float* __restrict__ W2, u16* __restrict__ W2P) {
    int pid = blockIdx.x * 256 + threadIdx.x;
    int e  = pid & 7;
    int l  = (pid >> 3) & 63;
    int cf = (pid >> 9) & 3;
    int ks = (pid >> 11) & 31;
    int w  = (pid >> 16) & 7;
    int n = w * 64 + cf * 16 + (l & 15);
    int k = ks * 32 + (l >> 4) * 8 + e;
    W2P[pid] = f2bf(W2[(size_t)k * DIM + n]);
}

// Frag-tile LDS layout (A-operands): each (16-row x 32-k) tile contiguous 1KB;
// elem (r,k) at u16 idx ((k>>3)&3)*128 + r*8 + (k&7).
// A-frag read = ds_read_b128 at tile*1024B + (lane>>4)*256 + (lane&15)*16 -> conflict-free.

__global__ __launch_bounds__(NTHR, 2) void ode_nocomm(
    const float* __restrict__ x0, const float* __restrict__ tgrid,
    const float* __restrict__ b1, const float* __restrict__ b2,
    const u16* __restrict__ W1P, const u16* __restrict__ W2P,
    float* __restrict__ out)
{
    __shared__ u16 hs[64 * 512];   // 64 KiB: h strip [32r][1024h] as 64 frag-tiles
    __shared__ u16 ys[32 * 512];   // 32 KiB: y strip [32r][512d]  as 32 frag-tiles

    const int tid  = threadIdx.x;
    const int lane = tid & 63;
    const int w    = tid >> 6;            // wave 0..7
    const int row0 = blockIdx.x * 32;     // block's private 32-row strip
    const int lr   = (lane >> 4) * 4;
    const int lc   = lane & 15;
    const int q    = lane >> 4;

    // RK4 state in registers
    float ybase[2][4][4];
    float kacc[2][4][4];

#pragma unroll
    for (int m = 0; m < 2; ++m)
#pragma unroll
        for (int cf = 0; cf < 4; ++cf)
#pragma unroll
            for (int j = 0; j < 4; ++j) {
                int row = row0 + m * 16 + lr + j;
                int col = w * 64 + cf * 16 + lc;
                float v = x0[(size_t)row * DIM + col];
                ybase[m][cf][j] = v;
                __builtin_nontemporal_store(v, &out[(size_t)row * DIM + col]);
                ys[((w * 2 + (cf >> 1)) * 2 + m) * 512 +
                   ((cf & 1) * 2 + (lc >> 3)) * 128 + (lr + j) * 8 + (lc & 7)] = f2bf(v);
            }

    float bv1[8], bv2[4];
#pragma unroll
    for (int cg = 0; cg < 8; ++cg) bv1[cg] = b1[w * 128 + cg * 16 + lc];
#pragma unroll
    for (int cf = 0; cf < 4; ++cf) bv2[cf] = b2[w * 64 + cf * 16 + lc];

    // packed weight base (per wave); frag load = 16B/lane, fully coalesced
    const u16* p1 = W1P + ((size_t)w << 16) + lane * 8;   // + (ks*8+cg)*512
    const u16* p2 = W2P + ((size_t)w << 16) + lane * 8;   // + (ks*4+cf)*512

    __syncthreads();

#pragma clang loop unroll(disable)
    for (int ev = 0; ev < 4 * (TSTEPS - 1); ++ev) {
        const int s  = ev >> 2;
        const int st = ev & 3;

        // ===== phase 1: h = tanh(y @ W1 + b1) -> hs  (two cg-halves, K=512) =====
#pragma unroll
        for (int hh = 0; hh < 2; ++hh) {
            f32x4 acc1[2][4];
#pragma unroll
            for (int m = 0; m < 2; ++m)
#pragma unroll
                for (int ci = 0; ci < 4; ++ci)
                    acc1[m][ci] = (f32x4){0.f, 0.f, 0.f, 0.f};

            s16x8 bA[4], bB[4];
#pragma unroll
            for (int ci = 0; ci < 4; ++ci)
                bA[ci] = *(const s16x8*)(p1 + (hh * 4 + ci) * 512);

#pragma unroll
            for (int ks = 0; ks < 16; ++ks) {
                s16x8* bc = (ks & 1) ? bB : bA;
                s16x8* bn = (ks & 1) ? bA : bB;
                if (ks < 15) {
#pragma unroll
                    for (int ci = 0; ci < 4; ++ci)
                        bn[ci] = *(const s16x8*)(p1 + ((ks + 1) * 8 + hh * 4 + ci) * 512);
                }
                s16x8 a0 = *(const s16x8*)&ys[(ks * 2 + 0) * 512 + q * 128 + lc * 8];
                s16x8 a1 = *(const s16x8*)&ys[(ks * 2 + 1) * 512 + q * 128 + lc * 8];
#pragma unroll
                for (int ci = 0; ci < 4; ++ci) {
                    acc1[0][ci] = __builtin_amdgcn_mfma_f32_16x16x32_bf16(a0, bc[ci], acc1[0][ci], 0, 0, 0);
                    acc1[1][ci] = __builtin_amdgcn_mfma_f32_16x16x32_bf16(a1, bc[ci], acc1[1][ci], 0, 0, 0);
                }
            }

#pragma unroll
            for (int m = 0; m < 2; ++m)
#pragma unroll
                for (int ci = 0; ci < 4; ++ci) {
                    int cg = hh * 4 + ci;
                    int tile = (w * 4 + (cg >> 1)) * 2 + m;
                    int base = tile * 512 + ((cg & 1) * 2 + (lc >> 3)) * 128 + (lc & 7);
#pragma unroll
                    for (int j = 0; j < 4; ++j)
                        hs[base + (lr + j) * 8] = f2bf(fast_tanh(acc1[m][ci][j] + bv1[cg]));
                }
        }
        __syncthreads();

        // ===== phase 2: k = h @ W2 + b2 ; RK4 in regs  (two cf-halves, K=1024) =====
        const float dtv = tgrid[s + 1] - tgrid[s];
        float* yn = out + (size_t)(s + 1) * BATCH * DIM;

#pragma unroll
        for (int fh = 0; fh < 2; ++fh) {
            f32x4 acc2[2][2];
#pragma unroll
            for (int m = 0; m < 2; ++m)
#pragma unroll
                for (int ci = 0; ci < 2; ++ci)
                    acc2[m][ci] = (f32x4){0.f, 0.f, 0.f, 0.f};

            s16x8 cA[2], cB[2];
#pragma unroll
            for (int ci = 0; ci < 2; ++ci)
                cA[ci] = *(const s16x8*)(p2 + (fh * 2 + ci) * 512);

#pragma unroll
            for (int ks = 0; ks < 32; ++ks) {
                s16x8* bc = (ks & 1) ? cB : cA;
                s16x8* bn = (ks & 1) ? cA : cB;
                if (ks < 31) {
#pragma unroll
                    for (int ci = 0; ci < 2; ++ci)
                        bn[ci] = *(const s16x8*)(p2 + ((ks + 1) * 4 + fh * 2 + ci) * 512);
                }
                s16x8 a0 = *(const s16x8*)&hs[(ks * 2 + 0) * 512 + q * 128 + lc * 8];
                s16x8 a1 = *(const s16x8*)&hs[(ks * 2 + 1) * 512 + q * 128 + lc * 8];
#pragma unroll
                for (int ci = 0; ci < 2; ++ci) {
                    acc2[0][ci] = __builtin_amdgcn_mfma_f32_16x16x32_bf16(a0, bc[ci], acc2[0][ci], 0, 0, 0);
                    acc2[1][ci] = __builtin_amdgcn_mfma_f32_16x16x32_bf16(a1, bc[ci], acc2[1][ci], 0, 0, 0);
                }
            }

#pragma unroll
            for (int m = 0; m < 2; ++m)
#pragma unroll
                for (int ci = 0; ci < 2; ++ci) {
                    int cf = fh * 2 + ci;
                    int ytile = (w * 2 + (cf >> 1)) * 2 + m;
                    int ybase_i = ytile * 512 + ((cf & 1) * 2 + (lc >> 3)) * 128 + (lc & 7);
#pragma unroll
                    for (int j = 0; j < 4; ++j) {
                        float v = acc2[m][ci][j] + bv2[cf];
                        float yb = ybase[m][cf][j];
                        float ywr;
                        if (st == 0) {
                            kacc[m][cf][j] = v;
                            ywr = yb + 0.5f * dtv * v;
                        } else if (st == 1) {
                            kacc[m][cf][j] += 2.0f * v;
                            ywr = yb + 0.5f * dtv * v;
                        } else if (st == 2) {
                            kacc[m][cf][j] += 2.0f * v;
                            ywr = yb + dtv * v;
                        } else {
                            float y1 = yb + (dtv * (1.0f / 6.0f)) * (kacc[m][cf][j] + v);
                            int row = row0 + m * 16 + lr + j;
                            int col = w * 64 + cf * 16 + lc;
                            __builtin_nontemporal_store(y1, &yn[(size_t)row * DIM + col]);
                            ybase[m][cf][j] = y1;
                            ywr = y1;
                        }
                        ys[ybase_i + (lr + j) * 8] = f2bf(ywr);
                    }
                }
        }
        __syncthreads();
    }
}

extern "C" void kernel_launch(void* const* d_in, const int* in_sizes, int n_in,
                              void* d_out, int out_size, void* d_ws, size_t ws_size,
                              hipStream_t stream) {
    (void)in_sizes; (void)n_in; (void)out_size; (void)ws_size;
    const float* x0 = (const float*)d_in[0];
    const float* t  = (const float*)d_in[1];
    const float* W1 = (const float*)d_in[2];
    const float* b1 = (const float*)d_in[3];
    const float* W2 = (const float*)d_in[4];
    const float* b2 = (const float*)d_in[5];
    float* out = (float*)d_out;

    char* ws = (char*)d_ws;
    u16* W1P = (u16*)(ws);              // 1 MB packed bf16 frag-order
    u16* W2P = (u16*)(ws + (1u << 20)); // 1 MB packed bf16 frag-order

    pack_w1<<<(HID * DIM) / 256, 256, 0, stream>>>(W1, W1P);
    pack_w2<<<(DIM * HID) / 256, 256, 0, stream>>>(W2, W2P);

    ode_nocomm<<<NBLK, NTHR, 0, stream>>>(x0, t, b1, b2, W1P, W2P, out);
}

// Round 8
// 7544.276 us; speedup vs baseline: 1.3973x; 1.3973x over previous
//
#include <hip/hip_runtime.h>
#include <hip/hip_bf16.h>
#include <cstdint>

#define BATCH 4096
#define DIM   512
#define HID   1024
#define TSTEPS 20
#define NBLK  128
#define NTHR  512

typedef unsigned short u16;
typedef short s16x8 __attribute__((ext_vector_type(8)));
typedef float f32x4 __attribute__((ext_vector_type(4)));

__device__ __forceinline__ u16 f2bf(float f) {
    unsigned int u = __float_as_uint(f);
    u = (u + 0x7FFFu + ((u >> 16) & 1u)) >> 16;   // RNE
    return (u16)u;
}

__device__ __forceinline__ float fast_tanh(float x) {
    float ax = __builtin_fabsf(x);
    float e  = __expf(2.0f * ax);                 // inf for large ax -> t = 1
    float t  = 1.0f - 2.0f * __builtin_amdgcn_rcpf(e + 1.0f);
    return __builtin_copysignf(t, x);
}

__global__ void zero_cnt(unsigned* cnt) { cnt[0] = 0u; }

// Pack W1 [512k][1024n] f32 -> W1P bf16 in MFMA B-frag order:
// u16 idx = (((w*16 + ks)*8 + cg)*64 + lane)*8 + e
__global__ void pack_w1(const float* __restrict__ W1, u16* __restrict__ W1P) {
    int pid = blockIdx.x * 256 + threadIdx.x;
    int e  = pid & 7;
    int l  = (pid >> 3) & 63;
    int cg = (pid >> 9) & 7;
    int ks = (pid >> 12) & 15;
    int w  = (pid >> 16) & 7;
    int n = w * 128 + cg * 16 + (l & 15);
    int k = ks * 32 + (l >> 4) * 8 + e;
    W1P[pid] = f2bf(W1[(size_t)k * HID + n]);
}

// Pack W2 [1024k][512n] f32 -> W2P bf16:
// u16 idx = (((w*32 + ks)*4 + cf)*64 + lane)*8 + e
__global__ void pack_w2(const float* __restrict__ W2, u16* __restrict__ W2P) {
    int pid = blockIdx.x * 256 + threadIdx.x;
    int e  = pid & 7;
    int l  = (pid >> 3) & 63;
    int cf = (pid >> 9) & 3;
    int ks = (pid >> 11) & 31;
    int w  = (pid >> 16) & 7;
    int n = w * 64 + cf * 16 + (l & 15);
    int k = ks * 32 + (l >> 4) * 8 + e;
    W2P[pid] = f2bf(W2[(size_t)k * DIM + n]);
}

// Frag-tile LDS layout (A-operands): each (16-row x 32-k) tile contiguous 1KB;
// elem (r,k) at u16 idx ((k>>3)&3)*128 + r*8 + (k&7).
// A-frag read = ds_read_b128 at tile*1024B + (lane>>4)*256 + (lane&15)*16 -> conflict-free.

__global__ __launch_bounds__(NTHR)
__attribute__((amdgpu_waves_per_eu(2, 2)))     // pin 2 waves/EU -> 256-VGPR budget, no spill
void ode_nocomm(
    const float* __restrict__ x0, const float* __restrict__ tgrid,
    const float* __restrict__ b1, const float* __restrict__ b2,
    const u16* __restrict__ W1P, const u16* __restrict__ W2P,
    float* __restrict__ out, unsigned* __restrict__ cnt)
{
    __shared__ u16 hs[64 * 512];   // 64 KiB: h strip [32r][1024h] as 64 frag-tiles
    __shared__ u16 ys[32 * 512];   // 32 KiB: y strip [32r][512d]  as 32 frag-tiles

    const int tid  = threadIdx.x;
    const int lane = tid & 63;
    const int w    = tid >> 6;            // wave 0..7
    const int row0 = blockIdx.x * 32;     // block's private 32-row strip
    const int lr   = (lane >> 4) * 4;
    const int lc   = lane & 15;
    const int q    = lane >> 4;

    // RK4 state in registers
    float ybase[2][4][4];
    float kacc[2][4][4];

#pragma unroll
    for (int m = 0; m < 2; ++m)
#pragma unroll
        for (int cf = 0; cf < 4; ++cf)
#pragma unroll
            for (int j = 0; j < 4; ++j) {
                int row = row0 + m * 16 + lr + j;
                int col = w * 64 + cf * 16 + lc;
                float v = x0[(size_t)row * DIM + col];
                ybase[m][cf][j] = v;
                out[(size_t)row * DIM + col] = v;
                ys[((w * 2 + (cf >> 1)) * 2 + m) * 512 +
                   ((cf & 1) * 2 + (lc >> 3)) * 128 + (lr + j) * 8 + (lc & 7)] = f2bf(v);
            }

    float bv1[8], bv2[4];
#pragma unroll
    for (int cg = 0; cg < 8; ++cg) bv1[cg] = b1[w * 128 + cg * 16 + lc];
#pragma unroll
    for (int cf = 0; cf < 4; ++cf) bv2[cf] = b2[w * 64 + cf * 16 + lc];

    // packed weight base (per wave); frag load = 16B/lane, fully coalesced
    const u16* p1 = W1P + ((size_t)w << 16) + lane * 8;   // + (ks*8+cg)*512
    const u16* p2 = W2P + ((size_t)w << 16) + lane * 8;   // + (ks*4+cf)*512

    __syncthreads();

#pragma clang loop unroll(disable)
    for (int ev = 0; ev < 4 * (TSTEPS - 1); ++ev) {
        const int s  = ev >> 2;
        const int st = ev & 3;

        // ========== phase 1: h = tanh(y @ W1 + b1) -> hs  (wave: 32r x 128c, K=512) ==========
        {
            f32x4 acc1[2][8];
#pragma unroll
            for (int m = 0; m < 2; ++m)
#pragma unroll
                for (int cg = 0; cg < 8; ++cg)
                    acc1[m][cg] = (f32x4){0.f, 0.f, 0.f, 0.f};

            s16x8 bA[8], bB[8];
#pragma unroll
            for (int cg = 0; cg < 8; ++cg)
                bA[cg] = *(const s16x8*)(p1 + cg * 512);

#pragma unroll
            for (int ks = 0; ks < 16; ++ks) {
                s16x8* bc = (ks & 1) ? bB : bA;
                s16x8* bn = (ks & 1) ? bA : bB;
                if (ks < 15) {
#pragma unroll
                    for (int cg = 0; cg < 8; ++cg)
                        bn[cg] = *(const s16x8*)(p1 + ((ks + 1) * 8 + cg) * 512);
                }
                s16x8 a0 = *(const s16x8*)&ys[(ks * 2 + 0) * 512 + q * 128 + lc * 8];
                s16x8 a1 = *(const s16x8*)&ys[(ks * 2 + 1) * 512 + q * 128 + lc * 8];
#pragma unroll
                for (int cg = 0; cg < 8; ++cg) {
                    acc1[0][cg] = __builtin_amdgcn_mfma_f32_16x16x32_bf16(a0, bc[cg], acc1[0][cg], 0, 0, 0);
                    acc1[1][cg] = __builtin_amdgcn_mfma_f32_16x16x32_bf16(a1, bc[cg], acc1[1][cg], 0, 0, 0);
                }
            }

#pragma unroll
            for (int m = 0; m < 2; ++m)
#pragma unroll
                for (int cg = 0; cg < 8; ++cg) {
                    int tile = (w * 4 + (cg >> 1)) * 2 + m;
                    int base = tile * 512 + ((cg & 1) * 2 + (lc >> 3)) * 128 + (lc & 7);
#pragma unroll
                    for (int j = 0; j < 4; ++j)
                        hs[base + (lr + j) * 8] = f2bf(fast_tanh(acc1[m][cg][j] + bv1[cg]));
                }
        }
        __syncthreads();

        // ========== phase 2: k = h @ W2 + b2 ; RK4 in regs  (wave: 32r x 64c, K=1024) ==========
        {
            f32x4 acc2[2][4];
#pragma unroll
            for (int m = 0; m < 2; ++m)
#pragma unroll
                for (int cf = 0; cf < 4; ++cf)
                    acc2[m][cf] = (f32x4){0.f, 0.f, 0.f, 0.f};

            s16x8 cA[4], cB[4];
#pragma unroll
            for (int cf = 0; cf < 4; ++cf)
                cA[cf] = *(const s16x8*)(p2 + cf * 512);

#pragma unroll
            for (int ks = 0; ks < 32; ++ks) {
                s16x8* bc = (ks & 1) ? cB : cA;
                s16x8* bn = (ks & 1) ? cA : cB;
                if (ks < 31) {
#pragma unroll
                    for (int cf = 0; cf < 4; ++cf)
                        bn[cf] = *(const s16x8*)(p2 + ((ks + 1) * 4 + cf) * 512);
                }
                s16x8 a0 = *(const s16x8*)&hs[(ks * 2 + 0) * 512 + q * 128 + lc * 8];
                s16x8 a1 = *(const s16x8*)&hs[(ks * 2 + 1) * 512 + q * 128 + lc * 8];
#pragma unroll
                for (int cf = 0; cf < 4; ++cf) {
                    acc2[0][cf] = __builtin_amdgcn_mfma_f32_16x16x32_bf16(a0, bc[cf], acc2[0][cf], 0, 0, 0);
                    acc2[1][cf] = __builtin_amdgcn_mfma_f32_16x16x32_bf16(a1, bc[cf], acc2[1][cf], 0, 0, 0);
                }
            }

            const float dtv = tgrid[s + 1] - tgrid[s];
            float* yn = out + (size_t)(s + 1) * BATCH * DIM;
#pragma unroll
            for (int m = 0; m < 2; ++m)
#pragma unroll
                for (int cf = 0; cf < 4; ++cf) {
                    int ytile = (w * 2 + (cf >> 1)) * 2 + m;
                    int ybase_i = ytile * 512 + ((cf & 1) * 2 + (lc >> 3)) * 128 + (lc & 7);
#pragma unroll
                    for (int j = 0; j < 4; ++j) {
                        float v = acc2[m][cf][j] + bv2[cf];
                        float yb = ybase[m][cf][j];
                        float ywr;
                        if (st == 0) {
                            kacc[m][cf][j] = v;
                            ywr = yb + 0.5f * dtv * v;
                        } else if (st == 1) {
                            kacc[m][cf][j] += 2.0f * v;
                            ywr = yb + 0.5f * dtv * v;
                        } else if (st == 2) {
                            kacc[m][cf][j] += 2.0f * v;
                            ywr = yb + dtv * v;
                        } else {
                            float y1 = yb + (dtv * (1.0f / 6.0f)) * (kacc[m][cf][j] + v);
                            int row = row0 + m * 16 + lr + j;
                            int col = w * 64 + cf * 16 + lc;
                            yn[(size_t)row * DIM + col] = y1;
                            ybase[m][cf][j] = y1;
                            ywr = y1;
                        }
                        ys[ybase_i + (lr + j) * 8] = f2bf(ywr);
                    }
                }
        }

        // ---- pacing barrier (pure temporal sync, no data dependency -> relaxed, no fences) ----
        __syncthreads();
        if (tid == 0) {
            __hip_atomic_fetch_add(cnt, 1u, __ATOMIC_RELAXED, __HIP_MEMORY_SCOPE_AGENT);
            unsigned target = (unsigned)(ev + 1) * NBLK;
            unsigned v;
            do {
                __builtin_amdgcn_s_sleep(8);
                v = __hip_atomic_load(cnt, __ATOMIC_RELAXED, __HIP_MEMORY_SCOPE_AGENT);
            } while (v < target);
        }
        __syncthreads();
    }
}

extern "C" void kernel_launch(void* const* d_in, const int* in_sizes, int n_in,
                              void* d_out, int out_size, void* d_ws, size_t ws_size,
                              hipStream_t stream) {
    (void)in_sizes; (void)n_in; (void)out_size; (void)ws_size;
    const float* x0 = (const float*)d_in[0];
    const float* t  = (const float*)d_in[1];
    const float* W1 = (const float*)d_in[2];
    const float* b1 = (const float*)d_in[3];
    const float* W2 = (const float*)d_in[4];
    const float* b2 = (const float*)d_in[5];
    float* out = (float*)d_out;

    char* ws = (char*)d_ws;
    u16*      W1P = (u16*)(ws);              // 1 MB packed bf16 frag-order
    u16*      W2P = (u16*)(ws + (1u << 20)); // 1 MB packed bf16 frag-order
    unsigned* cnt = (unsigned*)(ws + (2u << 20));

    zero_cnt<<<1, 1, 0, stream>>>(cnt);
    pack_w1<<<(HID * DIM) / 256, 256, 0, stream>>>(W1, W1P);
    pack_w2<<<(DIM * HID) / 256, 256, 0, stream>>>(W2, W2P);

    ode_nocomm<<<NBLK, NTHR, 0, stream>>>(x0, t, b1, b2, W1P, W2P, out, cnt);
}

// Round 9
// 7053.305 us; speedup vs baseline: 1.4945x; 1.0696x over previous
//
#include <hip/hip_runtime.h>
#include <hip/hip_bf16.h>
#include <cstdint>

#define BATCH 4096
#define DIM   512
#define HID   1024
#define TSTEPS 20
#define NBLK  128
#define NTHR  512

typedef unsigned short u16;
typedef short s16x8 __attribute__((ext_vector_type(8)));
typedef float f32x4 __attribute__((ext_vector_type(4)));

__device__ __forceinline__ u16 f2bf(float f) {
    unsigned int u = __float_as_uint(f);
    u = (u + 0x7FFFu + ((u >> 16) & 1u)) >> 16;   // RNE
    return (u16)u;
}

__device__ __forceinline__ float fast_tanh(float x) {
    float ax = __builtin_fabsf(x);
    float e  = __expf(2.0f * ax);                 // inf for large ax -> t = 1
    float t  = 1.0f - 2.0f * __builtin_amdgcn_rcpf(e + 1.0f);
    return __builtin_copysignf(t, x);
}

// Pack W1 [512k][1024n] f32 -> W1P bf16 in MFMA B-frag order:
// u16 idx = (((w*16 + ks)*8 + cg)*64 + lane)*8 + e
__global__ void pack_w1(const float* __restrict__ W1, u16* __restrict__ W1P) {
    int pid = blockIdx.x * 256 + threadIdx.x;
    int e  = pid & 7;
    int l  = (pid >> 3) & 63;
    int cg = (pid >> 9) & 7;
    int ks = (pid >> 12) & 15;
    int w  = (pid >> 16) & 7;
    int n = w * 128 + cg * 16 + (l & 15);
    int k = ks * 32 + (l >> 4) * 8 + e;
    W1P[pid] = f2bf(W1[(size_t)k * HID + n]);
}

// Pack W2 [1024k][512n] f32 -> W2P bf16:
// u16 idx = (((w*32 + ks)*4 + cf)*64 + lane)*8 + e
__global__ void pack_w2(const float* __restrict__ W2, u16* __restrict__ W2P) {
    int pid = blockIdx.x * 256 + threadIdx.x;
    int e  = pid & 7;
    int l  = (pid >> 3) & 63;
    int cf = (pid >> 9) & 3;
    int ks = (pid >> 11) & 31;
    int w  = (pid >> 16) & 7;
    int n = w * 64 + cf * 16 + (l & 15);
    int k = ks * 32 + (l >> 4) * 8 + e;
    W2P[pid] = f2bf(W2[(size_t)k * DIM + n]);
}

// Frag-tile LDS layout (A-operands): each (16-row x 32-k) tile contiguous 1KB;
// elem (r,k) at u16 idx ((k>>3)&3)*128 + r*8 + (k&7).
// A-frag read = ds_read_b128 at tile*1024B + (lane>>4)*256 + (lane&15)*16 -> conflict-free.

__global__ __launch_bounds__(NTHR, 2)   // min 2 waves/EU -> 256-VGPR cap (kill the spill)
void ode_nocomm(
    const float* __restrict__ x0, const float* __restrict__ tgrid,
    const float* __restrict__ b1, const float* __restrict__ b2,
    const u16* __restrict__ W1P, const u16* __restrict__ W2P,
    float* __restrict__ out)
{
    __shared__ u16 hs[64 * 512];   // 64 KiB: h strip [32r][1024h] as 64 frag-tiles
    __shared__ u16 ys[32 * 512];   // 32 KiB: y strip [32r][512d]  as 32 frag-tiles

    const int tid  = threadIdx.x;
    const int lane = tid & 63;
    const int w    = tid >> 6;            // wave 0..7
    const int row0 = blockIdx.x * 32;     // block's private 32-row strip
    const int lr   = (lane >> 4) * 4;
    const int lc   = lane & 15;
    const int q    = lane >> 4;

    // RK4 state in registers
    float ybase[2][4][4];
    float kacc[2][4][4];

#pragma unroll
    for (int m = 0; m < 2; ++m)
#pragma unroll
        for (int cf = 0; cf < 4; ++cf)
#pragma unroll
            for (int j = 0; j < 4; ++j) {
                int row = row0 + m * 16 + lr + j;
                int col = w * 64 + cf * 16 + lc;
                float v = x0[(size_t)row * DIM + col];
                ybase[m][cf][j] = v;
                out[(size_t)row * DIM + col] = v;
                ys[((w * 2 + (cf >> 1)) * 2 + m) * 512 +
                   ((cf & 1) * 2 + (lc >> 3)) * 128 + (lr + j) * 8 + (lc & 7)] = f2bf(v);
            }

    float bv1[8], bv2[4];
#pragma unroll
    for (int cg = 0; cg < 8; ++cg) bv1[cg] = b1[w * 128 + cg * 16 + lc];
#pragma unroll
    for (int cf = 0; cf < 4; ++cf) bv2[cf] = b2[w * 64 + cf * 16 + lc];

    // packed weight base (per wave); frag load = 16B/lane, fully coalesced
    const u16* p1 = W1P + ((size_t)w << 16) + lane * 8;   // + (ks*8+cg)*512
    const u16* p2 = W2P + ((size_t)w << 16) + lane * 8;   // + (ks*4+cf)*512

    __syncthreads();

#pragma clang loop unroll(disable)
    for (int ev = 0; ev < 4 * (TSTEPS - 1); ++ev) {
        const int s  = ev >> 2;
        const int st = ev & 3;

        // ========== phase 1: h = tanh(y @ W1 + b1) -> hs  (wave: 32r x 128c, K=512) ==========
        {
            f32x4 acc1[2][8];
#pragma unroll
            for (int m = 0; m < 2; ++m)
#pragma unroll
                for (int cg = 0; cg < 8; ++cg)
                    acc1[m][cg] = (f32x4){0.f, 0.f, 0.f, 0.f};

            s16x8 bA[8], bB[8];
#pragma unroll
            for (int cg = 0; cg < 8; ++cg)
                bA[cg] = *(const s16x8*)(p1 + cg * 512);

#pragma unroll
            for (int ks = 0; ks < 16; ++ks) {
                s16x8* bc = (ks & 1) ? bB : bA;
                s16x8* bn = (ks & 1) ? bA : bB;
                if (ks < 15) {
#pragma unroll
                    for (int cg = 0; cg < 8; ++cg)
                        bn[cg] = *(const s16x8*)(p1 + ((ks + 1) * 8 + cg) * 512);
                }
                s16x8 a0 = *(const s16x8*)&ys[(ks * 2 + 0) * 512 + q * 128 + lc * 8];
                s16x8 a1 = *(const s16x8*)&ys[(ks * 2 + 1) * 512 + q * 128 + lc * 8];
#pragma unroll
                for (int cg = 0; cg < 8; ++cg) {
                    acc1[0][cg] = __builtin_amdgcn_mfma_f32_16x16x32_bf16(a0, bc[cg], acc1[0][cg], 0, 0, 0);
                    acc1[1][cg] = __builtin_amdgcn_mfma_f32_16x16x32_bf16(a1, bc[cg], acc1[1][cg], 0, 0, 0);
                }
            }

#pragma unroll
            for (int m = 0; m < 2; ++m)
#pragma unroll
                for (int cg = 0; cg < 8; ++cg) {
                    int tile = (w * 4 + (cg >> 1)) * 2 + m;
                    int base = tile * 512 + ((cg & 1) * 2 + (lc >> 3)) * 128 + (lc & 7);
#pragma unroll
                    for (int j = 0; j < 4; ++j)
                        hs[base + (lr + j) * 8] = f2bf(fast_tanh(acc1[m][cg][j] + bv1[cg]));
                }
        }
        __syncthreads();

        // ========== phase 2: k = h @ W2 + b2 ; RK4 in regs  (wave: 32r x 64c, K=1024) ==========
        {
            f32x4 acc2[2][4];
#pragma unroll
            for (int m = 0; m < 2; ++m)
#pragma unroll
                for (int cf = 0; cf < 4; ++cf)
                    acc2[m][cf] = (f32x4){0.f, 0.f, 0.f, 0.f};

            s16x8 cA[4], cB[4];
#pragma unroll
            for (int cf = 0; cf < 4; ++cf)
                cA[cf] = *(const s16x8*)(p2 + cf * 512);

#pragma unroll
            for (int ks = 0; ks < 32; ++ks) {
                s16x8* bc = (ks & 1) ? cB : cA;
                s16x8* bn = (ks & 1) ? cA : cB;
                if (ks < 31) {
#pragma unroll
                    for (int cf = 0; cf < 4; ++cf)
                        bn[cf] = *(const s16x8*)(p2 + ((ks + 1) * 4 + cf) * 512);
                }
                s16x8 a0 = *(const s16x8*)&hs[(ks * 2 + 0) * 512 + q * 128 + lc * 8];
                s16x8 a1 = *(const s16x8*)&hs[(ks * 2 + 1) * 512 + q * 128 + lc * 8];
#pragma unroll
                for (int cf = 0; cf < 4; ++cf) {
                    acc2[0][cf] = __builtin_amdgcn_mfma_f32_16x16x32_bf16(a0, bc[cf], acc2[0][cf], 0, 0, 0);
                    acc2[1][cf] = __builtin_amdgcn_mfma_f32_16x16x32_bf16(a1, bc[cf], acc2[1][cf], 0, 0, 0);
                }
            }

            const float dtv = tgrid[s + 1] - tgrid[s];
            float* yn = out + (size_t)(s + 1) * BATCH * DIM;
#pragma unroll
            for (int m = 0; m < 2; ++m)
#pragma unroll
                for (int cf = 0; cf < 4; ++cf) {
                    int ytile = (w * 2 + (cf >> 1)) * 2 + m;
                    int ybase_i = ytile * 512 + ((cf & 1) * 2 + (lc >> 3)) * 128 + (lc & 7);
#pragma unroll
                    for (int j = 0; j < 4; ++j) {
                        float v = acc2[m][cf][j] + bv2[cf];
                        float yb = ybase[m][cf][j];
                        float ywr;
                        if (st == 0) {
                            kacc[m][cf][j] = v;
                            ywr = yb + 0.5f * dtv * v;
                        } else if (st == 1) {
                            kacc[m][cf][j] += 2.0f * v;
                            ywr = yb + 0.5f * dtv * v;
                        } else if (st == 2) {
                            kacc[m][cf][j] += 2.0f * v;
                            ywr = yb + dtv * v;
                        } else {
                            float y1 = yb + (dtv * (1.0f / 6.0f)) * (kacc[m][cf][j] + v);
                            int row = row0 + m * 16 + lr + j;
                            int col = w * 64 + cf * 16 + lc;
                            yn[(size_t)row * DIM + col] = y1;
                            ybase[m][cf][j] = y1;
                            ywr = y1;
                        }
                        ys[ybase_i + (lr + j) * 8] = f2bf(ywr);
                    }
                }
        }
        __syncthreads();
    }
}

extern "C" void kernel_launch(void* const* d_in, const int* in_sizes, int n_in,
                              void* d_out, int out_size, void* d_ws, size_t ws_size,
                              hipStream_t stream) {
    (void)in_sizes; (void)n_in; (void)out_size; (void)ws_size;
    const float* x0 = (const float*)d_in[0];
    const float* t  = (const float*)d_in[1];
    const float* W1 = (const float*)d_in[2];
    const float* b1 = (const float*)d_in[3];
    const float* W2 = (const float*)d_in[4];
    const float* b2 = (const float*)d_in[5];
    float* out = (float*)d_out;

    char* ws = (char*)d_ws;
    u16* W1P = (u16*)(ws);              // 1 MB packed bf16 frag-order
    u16* W2P = (u16*)(ws + (1u << 20)); // 1 MB packed bf16 frag-order

    pack_w1<<<(HID * DIM) / 256, 256, 0, stream>>>(W1, W1P);
    pack_w2<<<(DIM * HID) / 256, 256, 0, stream>>>(W2, W2P);

    ode_nocomm<<<NBLK, NTHR, 0, stream>>>(x0, t, b1, b2, W1P, W2P, out);
}

// Round 11
// 2020.462 us; speedup vs baseline: 5.2173x; 3.4909x over previous
//
#include <hip/hip_runtime.h>
#include <hip/hip_bf16.h>
#include <cstdint>

#define BATCH 4096
#define DIM   512
#define HID   1024
#define TSTEPS 20

typedef unsigned short u16;
typedef short s16x8 __attribute__((ext_vector_type(8)));
typedef float f32x4 __attribute__((ext_vector_type(4)));

__device__ __forceinline__ u16 f2bf(float f) {
    unsigned int u = __float_as_uint(f);
    u = (u + 0x7FFFu + ((u >> 16) & 1u)) >> 16;   // RNE
    return (u16)u;
}

// out[0] = x0 ; ybf = bf16(x0)
__global__ void init_state(const float* __restrict__ x0, float* __restrict__ out0,
                           u16* __restrict__ ybf, int n) {
    int i = blockIdx.x * blockDim.x + threadIdx.x;
    if (i < n) { float v = x0[i]; out0[i] = v; ybf[i] = f2bf(v); }
}

// Wt[n*K + k] = bf16(W[k*N + n])   (W is [K][N] row-major)
__global__ void transpose_convert(const float* __restrict__ W, u16* __restrict__ Wt,
                                  int K, int N) {
    int n = blockIdx.x * 32 + threadIdx.x;
    int k = blockIdx.y * 8  + threadIdx.y;
    if (n < N && k < K) Wt[(size_t)n * K + k] = f2bf(W[(size_t)k * N + n]);
}

// C = A[M,K] * Bt[N,K]^T, fused epilogue. 3-buffer depth-2 pipelined K-loop
// with counted vmcnt (T3/T4): stage(t+2) in flight while computing t.
// EPI==0 : act = bf16(tanh(C + bias))           (GEMM1)
// EPI==1..4 : RK4 stage epilogues               (GEMM2, N == DIM)
template<int BM, int BN, int EPI>
__global__ __launch_bounds__(256, 2) void gemm_bt(
    const u16* __restrict__ A,
    const u16* __restrict__ Bt,
    const float* __restrict__ bias,
    int M, int N, int K,
    u16* __restrict__ actOut,
    const float* __restrict__ ybase,
    float* __restrict__ ynext,
    float* __restrict__ accum,
    u16* __restrict__ ybf,
    const float* __restrict__ tgrid, int step)
{
    constexpr int AC = BM / 8;          // A chunks (1 KiB each) per K-tile
    constexpr int BC = BN / 8;
    constexpr int CPW = (AC + BC) / 4;  // global_load_lds per thread per tile
    static_assert(CPW == 4 || CPW == 6, "vmcnt literals below assume 4 or 6");
    constexpr int WM = BM / 32;
    constexpr int WN = BN / 32;
    constexpr int BUFE = (BM + BN) * 64;   // u16 elems per LDS buffer

    __shared__ u16 lds[3 * BUFE];

    const int tid  = threadIdx.x;
    const int lane = tid & 63;
    const int wid  = tid >> 6;
    const int wy   = wid >> 1;
    const int wx   = wid & 1;
    const int brow = blockIdx.x * BM;
    const int bcol = blockIdx.y * BN;

    const int srow = lane >> 3;                    // row within 8-row group
    const int scol = ((lane & 7) ^ srow) * 8;      // pre-swizzled k offset (elems)

    f32x4 acc[WM][WN];
#pragma unroll
    for (int m = 0; m < WM; ++m)
#pragma unroll
        for (int n = 0; n < WN; ++n)
            acc[m][n] = (f32x4){0.f, 0.f, 0.f, 0.f};

    auto stage = [&](int buf, int kt) {
        const int k0 = kt * 64;
        u16* base = &lds[buf * BUFE];
#pragma unroll
        for (int c0 = 0; c0 < CPW; ++c0) {
            int c = wid * CPW + c0;            // wave-uniform
            if (c < AC) {
                int row = c * 8 + srow;
                const u16* g = A + (size_t)(brow + row) * K + k0 + scol;
                __builtin_amdgcn_global_load_lds(
                    (const __attribute__((address_space(1))) unsigned int*)g,
                    (__attribute__((address_space(3))) unsigned int*)&base[c * 512],
                    16, 0, 0);
            } else {
                int cb = c - AC;
                int row = cb * 8 + srow;
                const u16* g = Bt + (size_t)(bcol + row) * K + k0 + scol;
                __builtin_amdgcn_global_load_lds(
                    (const __attribute__((address_space(1))) unsigned int*)g,
                    (__attribute__((address_space(3))) unsigned int*)&base[BM * 64 + cb * 512],
                    16, 0, 0);
            }
        }
    };

    const int NT = K / 64;

    // prologue: two tiles in flight
    stage(0, 0);
    stage(1, 1);

    for (int kt = 0; kt < NT; ++kt) {
        // wait for tile kt's loads (oldest); keep tile kt+1's in flight
        if (kt < NT - 1) {
            if constexpr (CPW == 6) asm volatile("s_waitcnt vmcnt(6)" ::: "memory");
            else                    asm volatile("s_waitcnt vmcnt(4)" ::: "memory");
        } else {
            asm volatile("s_waitcnt vmcnt(0)" ::: "memory");
        }
        __builtin_amdgcn_s_barrier();

        const char* lb = (const char*)&lds[(kt % 3) * BUFE];

        s16x8 af[2][WM], bfr[2][WN];
#pragma unroll
        for (int ks = 0; ks < 2; ++ks) {
#pragma unroll
            for (int m = 0; m < WM; ++m) {
                int row = wy * (BM / 2) + m * 16 + (lane & 15);
                unsigned byte = (unsigned)(row * 128 + (ks * 32 + (lane >> 4) * 8) * 2);
                byte ^= (unsigned)((row & 7) << 4);
                af[ks][m] = *(const s16x8*)(lb + byte);
            }
#pragma unroll
            for (int n = 0; n < WN; ++n) {
                int row = wx * (BN / 2) + n * 16 + (lane & 15);
                unsigned byte = (unsigned)(BM * 128 + row * 128 + (ks * 32 + (lane >> 4) * 8) * 2);
                byte ^= (unsigned)((row & 7) << 4);
                bfr[ks][n] = *(const s16x8*)(lb + byte);
            }
        }

        // issue tile kt+2 while tile kt computes (depth-2 prefetch)
        if (kt + 2 < NT) stage((kt + 2) % 3, kt + 2);

#pragma unroll
        for (int ks = 0; ks < 2; ++ks)
#pragma unroll
            for (int m = 0; m < WM; ++m)
#pragma unroll
                for (int n = 0; n < WN; ++n)
                    acc[m][n] = __builtin_amdgcn_mfma_f32_16x16x32_bf16(
                        af[ks][m], bfr[ks][n], acc[m][n], 0, 0, 0);

        // WAR guard: tile kt+3 (same buffer as kt) may not be staged until all
        // waves finished reading tile kt (reads completed before MFMA issue).
        __builtin_amdgcn_s_barrier();
    }

    // ---- epilogue ----
    float dtv = 0.f;
    if constexpr (EPI >= 1) dtv = tgrid[step + 1] - tgrid[step];

#pragma unroll
    for (int m = 0; m < WM; ++m) {
        int row0 = brow + wy * (BM / 2) + m * 16 + (lane >> 4) * 4;
#pragma unroll
        for (int n = 0; n < WN; ++n) {
            int col = bcol + wx * (BN / 2) + n * 16 + (lane & 15);
            float bv = bias[col];
#pragma unroll
            for (int j = 0; j < 4; ++j) {
                int row = row0 + j;
                float v = acc[m][n][j] + bv;
                if constexpr (EPI == 0) {
                    actOut[(size_t)row * HID + col] = f2bf(tanhf(v));
                } else {
                    size_t idx = (size_t)row * DIM + col;
                    float yb = ybase[idx];
                    if constexpr (EPI == 1) {
                        accum[idx] = v;
                        ybf[idx] = f2bf(yb + 0.5f * dtv * v);
                    } else if constexpr (EPI == 2) {
                        accum[idx] += 2.0f * v;
                        ybf[idx] = f2bf(yb + 0.5f * dtv * v);
                    } else if constexpr (EPI == 3) {
                        accum[idx] += 2.0f * v;
                        ybf[idx] = f2bf(yb + dtv * v);
                    } else {  // EPI == 4
                        float yn = yb + (dtv * (1.0f / 6.0f)) * (accum[idx] + v);
                        ynext[idx] = yn;
                        ybf[idx] = f2bf(yn);
                    }
                }
            }
        }
    }
}

extern "C" void kernel_launch(void* const* d_in, const int* in_sizes, int n_in,
                              void* d_out, int out_size, void* d_ws, size_t ws_size,
                              hipStream_t stream) {
    (void)in_sizes; (void)n_in; (void)out_size; (void)ws_size;
    const float* x0 = (const float*)d_in[0];
    const float* t  = (const float*)d_in[1];
    const float* W1 = (const float*)d_in[2];
    const float* b1 = (const float*)d_in[3];
    const float* W2 = (const float*)d_in[4];
    const float* b2 = (const float*)d_in[5];
    float* out = (float*)d_out;

    char* ws = (char*)d_ws;
    u16*   ybf   = (u16*)  (ws);               //  4 MB  [4096,512]  bf16
    u16*   act   = (u16*)  (ws + (4u  << 20)); //  8 MB  [4096,1024] bf16
    float* accum = (float*)(ws + (12u << 20)); //  8 MB  [4096,512]  f32
    u16*   W1T   = (u16*)  (ws + (20u << 20)); //  1 MB  [1024,512]  bf16
    u16*   W2T   = (u16*)  (ws + (21u << 20)); //  1 MB  [512,1024]  bf16

    init_state<<<(BATCH * DIM + 255) / 256, 256, 0, stream>>>(x0, out, ybf, BATCH * DIM);
    transpose_convert<<<dim3(HID / 32, DIM / 8), dim3(32, 8), 0, stream>>>(W1, W1T, DIM, HID);
    transpose_convert<<<dim3(DIM / 32, HID / 8), dim3(32, 8), 0, stream>>>(W2, W2T, HID, DIM);

    dim3 blk(256);
    dim3 g1(BATCH / 128, HID / 64);    // 32 x 16 = 512 blocks (2 per CU)
    dim3 g2(BATCH / 64,  DIM / 64);    // 64 x 8  = 512 blocks (2 per CU)

    for (int s = 0; s < TSTEPS - 1; ++s) {
        const float* yb_s = out + (size_t)s * BATCH * DIM;
        float*       yn_s = out + (size_t)(s + 1) * BATCH * DIM;

        // stage 1: k1 = f(y)
        gemm_bt<128,64,0><<<g1, blk, 0, stream>>>(ybf, W1T, b1, BATCH, HID, DIM,
                                                  act, nullptr, nullptr, nullptr, nullptr, nullptr, 0);
        gemm_bt<64,64,1><<<g2, blk, 0, stream>>>(act, W2T, b2, BATCH, DIM, HID,
                                                 nullptr, yb_s, yn_s, accum, ybf, t, s);
        // stage 2: k2 = f(y + dt/2 * k1)
        gemm_bt<128,64,0><<<g1, blk, 0, stream>>>(ybf, W1T, b1, BATCH, HID, DIM,
                                                  act, nullptr, nullptr, nullptr, nullptr, nullptr, 0);
        gemm_bt<64,64,2><<<g2, blk, 0, stream>>>(act, W2T, b2, BATCH, DIM, HID,
                                                 nullptr, yb_s, yn_s, accum, ybf, t, s);
        // stage 3: k3 = f(y + dt/2 * k2)
        gemm_bt<128,64,0><<<g1, blk, 0, stream>>>(ybf, W1T, b1, BATCH, HID, DIM,
                                                  act, nullptr, nullptr, nullptr, nullptr, nullptr, 0);
        gemm_bt<64,64,3><<<g2, blk, 0, stream>>>(act, W2T, b2, BATCH, DIM, HID,
                                                 nullptr, yb_s, yn_s, accum, ybf, t, s);
        // stage 4: y' = y + dt/6 * (k1 + 2k2 + 2k3 + k4)
        gemm_bt<128,64,0><<<g1, blk, 0, stream>>>(ybf, W1T, b1, BATCH, HID, DIM,
                                                  act, nullptr, nullptr, nullptr, nullptr, nullptr, 0);
        gemm_bt<64,64,4><<<g2, blk, 0, stream>>>(act, W2T, b2, BATCH, DIM, HID,
                                                 nullptr, yb_s, yn_s, accum, ybf, t, s);
    }
}